// Round 1
// baseline (1848.793 us; speedup 1.0000x reference)
//
#include <hip/hip_runtime.h>
#include <cstdint>

typedef _Float16 f16;
typedef _Float16 h8 __attribute__((ext_vector_type(8)));
typedef _Float16 h4 __attribute__((ext_vector_type(4)));
typedef float f4 __attribute__((ext_vector_type(4)));

#define NB 1024
#define NT 250
#define IND 158
#define KP0 160
#define NH 128
#define NG 512
#define LN_EPS 1e-5f

// ---------------- K0: weight fp32 -> f16 with padding/zero-fill ----------------
__global__ __launch_bounds__(256) void k_prep(const float* __restrict__ src, f16* __restrict__ dst,
                                              int srows, int scols, int dcols, int total) {
  int i = blockIdx.x * 256 + threadIdx.x;
  if (i >= total) return;
  int r = i / dcols, c = i - r * dcols;
  float v = (r < srows && c < scols) ? src[r * scols + c] : 0.f;
  dst[i] = (f16)v;
}

// ---------------- K_T: LayerNorm -> xn f16 [B][tc][160] ----------------
__global__ __launch_bounds__(256) void k_ln(const float* __restrict__ x, const float* __restrict__ gamma,
                                            const float* __restrict__ beta, f16* __restrict__ xn,
                                            int t0, int tc) {
  int tid = threadIdx.x;
  int sub = tid & 7;            // 8 threads per row
  int rloc = tid >> 3;          // 32 rows per block
  long long rowi = (long long)blockIdx.x * 32 + rloc;   // row over [B][tc]
  int b = (int)(rowi / tc), t = (int)(rowi % tc);
  const float* xr = x + ((long long)b * NT + (t0 + t)) * IND;
  float vals[20];
  float s = 0.f, ss = 0.f;
#pragma unroll
  for (int i = 0; i < 20; i++) {
    int k = sub + 8 * i;
    float v = (k < IND) ? xr[k] : 0.f;
    vals[i] = v; s += v; ss += v * v;
  }
  s += __shfl_xor(s, 1); ss += __shfl_xor(ss, 1);
  s += __shfl_xor(s, 2); ss += __shfl_xor(ss, 2);
  s += __shfl_xor(s, 4); ss += __shfl_xor(ss, 4);
  float mu = s * (1.f / IND);
  float var = ss * (1.f / IND) - mu * mu;
  float rs = rsqrtf(var + LN_EPS);
  f16* outr = xn + ((long long)b * tc + t) * KP0;
#pragma unroll
  for (int i = 0; i < 20; i++) {
    int k = sub + 8 * i;
    float v = (k < IND) ? (vals[i] - mu) * rs * gamma[k] + beta[k] : 0.f;
    outr[k] = (f16)v;   // k in [0,160): zero-fills K-pad
  }
}

// ---------------- K1/K3: xg = inp @ W^T + bias  (MFMA f16) ----------------
// inp: TRANS ? [tc][KP][1024] (f16) : rows [b][tc][KP] (f16);  W: [512][KP] f16
// xg out: [tc][1024][512] f16
template <int KP, bool TRANS>
__global__ __launch_bounds__(256, 1) void k_gates(const f16* __restrict__ inp, const f16* __restrict__ W,
                                                  const float* __restrict__ bias, f16* __restrict__ xg, int tc) {
  constexpr int KPP = KP + 8;      // pad: row stride multiple of 16B
  constexpr int KS = KP / 32;
  extern __shared__ f16 lds[];
  f16* Al = lds;                   // [128][KPP]  input rows (b)
  f16* Bl = lds + 128 * KPP;       // [128][KPP]  W rows (gates)
  int t = blockIdx.x, gs = blockIdx.y, bs = blockIdx.z;
  int tid = threadIdx.x;
  {
    int row = tid >> 1, half = tid & 1;
    if (TRANS) {
      const f16* base = inp + (long long)t * KP * NB + bs * 128 + row;
      for (int i = 0; i < KP / 2; i++) {
        int k = half * (KP / 2) + i;
        Al[row * KPP + k] = base[(long long)k * NB];
      }
    } else {
      const float4* srca = (const float4*)(inp + ((long long)(bs * 128 + row) * tc + t) * KP) + half * (KP / 16);
      float4* dsta = (float4*)(Al + row * KPP) + half * (KP / 16);
#pragma unroll
      for (int i = 0; i < KP / 16; i++) dsta[i] = srca[i];
    }
    const float4* srcb = (const float4*)(W + (gs * 128 + row) * KP) + half * (KP / 16);
    float4* dstb = (float4*)(Bl + row * KPP) + half * (KP / 16);
#pragma unroll
    for (int i = 0; i < KP / 16; i++) dstb[i] = srcb[i];
  }
  __syncthreads();
  int w = tid >> 6, lane = tid & 63, l15 = lane & 15, q = lane >> 4;
  // B-fragments: wave w owns gate n-tiles {2w, 2w+1}
  h8 bf[2][KS];
#pragma unroll
  for (int n2 = 0; n2 < 2; n2++)
#pragma unroll
    for (int ks = 0; ks < KS; ks++)
      bf[n2][ks] = *(const h8*)(Bl + (32 * w + 16 * n2 + l15) * KPP + 32 * ks + 8 * q);
  f4 acc[8][2];
#pragma unroll
  for (int n2 = 0; n2 < 2; n2++) {
    float bv = bias[gs * 128 + 32 * w + 16 * n2 + l15];
#pragma unroll
    for (int mt = 0; mt < 8; mt++) acc[mt][n2] = (f4){bv, bv, bv, bv};
  }
#pragma unroll
  for (int mt = 0; mt < 8; mt++) {
    h8 af[KS];
#pragma unroll
    for (int ks = 0; ks < KS; ks++)
      af[ks] = *(const h8*)(Al + (16 * mt + l15) * KPP + 32 * ks + 8 * q);
#pragma unroll
    for (int n2 = 0; n2 < 2; n2++)
#pragma unroll
      for (int ks = 0; ks < KS; ks++)
        acc[mt][n2] = __builtin_amdgcn_mfma_f32_16x16x32_f16(af[ks], bf[n2][ks], acc[mt][n2], 0, 0, 0);
  }
  f16* ob = xg + ((long long)t * NB + bs * 128) * NG + gs * 128 + 32 * w + l15;
#pragma unroll
  for (int mt = 0; mt < 8; mt++)
#pragma unroll
    for (int n2 = 0; n2 < 2; n2++)
#pragma unroll
      for (int r = 0; r < 4; r++)
        ob[(long long)(16 * mt + 4 * q + r) * NG + 16 * n2] = (f16)acc[mt][n2][r];
}

// ---------------- K2/K4: LSTM recurrence (persistent over chunk) ----------------
// xg: [tc][1024][512] f16; Whh: [512][136] f16 (padded); hseq out: [tc][128][1024] f16
__global__ __launch_bounds__(512, 2) void k_lstm(const f16* __restrict__ xg, const f16* __restrict__ Whh,
                                                 f16* __restrict__ hseq, float* __restrict__ carry_h,
                                                 float* __restrict__ carry_c, int tc, int first) {
  __shared__ f16 hbuf[2][16][136];
  int tid = threadIdx.x;
  int w = tid >> 6, lane = tid & 63, l15 = lane & 15, q = lane >> 4;
  int b0 = blockIdx.x * 16;
  for (int i = tid; i < 2176; i += 512) {
    int n = i / 136, k = i - n * 136;
    float hv = (!first && k < NH) ? carry_h[(b0 + n) * NH + k] : 0.f;
    hbuf[0][n][k] = (f16)hv;
  }
  int jbase = 16 * w + 4 * q;     // this lane's hidden-unit base (C-layout row)
  float c[4];
#pragma unroll
  for (int r = 0; r < 4; r++)
    c[r] = first ? 0.f : carry_c[(b0 + l15) * NH + jbase + r];
  // W_hh A-fragments: register-resident for the whole chunk (64 VGPRs)
  h8 af[4][4];
#pragma unroll
  for (int g = 0; g < 4; g++)
#pragma unroll
    for (int ks = 0; ks < 4; ks++)
      af[g][ks] = *(const h8*)(Whh + (128 * g + 16 * w + l15) * 136 + 32 * ks + 8 * q);
  __syncthreads();
  for (int t = 0; t < tc; t++) {
    int p = t & 1;
    f4 acc[4];
    const f16* xgr = xg + ((long long)t * NB + b0 + l15) * NG + jbase;
#pragma unroll
    for (int g = 0; g < 4; g++) {
      h4 xv = *(const h4*)(xgr + 128 * g);
#pragma unroll
      for (int r = 0; r < 4; r++) acc[g][r] = (float)xv[r];
    }
    h8 bf[4];
#pragma unroll
    for (int ks = 0; ks < 4; ks++)
      bf[ks] = *(const h8*)(&hbuf[p][l15][32 * ks + 8 * q]);
#pragma unroll
    for (int g = 0; g < 4; g++)
#pragma unroll
      for (int ks = 0; ks < 4; ks++)
        acc[g] = __builtin_amdgcn_mfma_f32_16x16x32_f16(af[g][ks], bf[ks], acc[g], 0, 0, 0);
    f16* hgl = hseq + (long long)t * NH * NB + b0 + l15;
    h4 hv4;
#pragma unroll
    for (int r = 0; r < 4; r++) {
      float iv = 1.f / (1.f + __expf(-acc[0][r]));
      float fv = 1.f / (1.f + __expf(-acc[1][r]));
      float gv = 1.f - 2.f / (__expf(2.f * acc[2][r]) + 1.f);
      float ov = 1.f / (1.f + __expf(-acc[3][r]));
      float cn = fv * c[r] + iv * gv;
      c[r] = cn;
      float hv = ov * (1.f - 2.f / (__expf(2.f * cn) + 1.f));
      f16 hh = (f16)hv;
      hv4[r] = hh;
      hgl[(long long)(jbase + r) * NB] = hh;
    }
    *(h4*)(&hbuf[1 - p][l15][jbase]) = hv4;
    __syncthreads();
  }
#pragma unroll
  for (int r = 0; r < 4; r++)
    carry_c[(b0 + l15) * NH + jbase + r] = c[r];
  int pf = tc & 1;
  for (int i = tid; i < 2048; i += 512) {
    int n = i >> 7, k = i & 127;
    carry_h[(b0 + n) * NH + k] = (float)hbuf[pf][n][k];
  }
}

// ---------------- K5: out = relu(h1 @ Wp1^T + bp1) @ Wp2^T + bp2 ----------------
__global__ __launch_bounds__(256, 1) void k_proj(const f16* __restrict__ hseq, const f16* __restrict__ Wp1f,
                                                 const f16* __restrict__ Wp2f, const float* __restrict__ bp1,
                                                 const float* __restrict__ bp2, float* __restrict__ out,
                                                 int tc, int t0) {
  extern __shared__ f16 lds[];
  f16* hl = lds;                  // [128][136]
  f16* w1 = hl + 128 * 136;       // [64][136]
  f16* w2 = w1 + 64 * 136;        // [32][72]
  f16* pl = w2 + 32 * 72;         // [128][72]
  int t = blockIdx.x, bs = blockIdx.y;
  int tid = threadIdx.x;
  {
    int b = tid >> 1, half = tid & 1;
    const f16* base = hseq + (long long)t * NH * NB + bs * 128 + b;
    for (int i = 0; i < 64; i++) {
      int k = half * 64 + i;
      hl[b * 136 + k] = base[(long long)k * NB];
    }
    if (tid < 128) {
      int row = tid >> 1;
      const float4* s = (const float4*)(Wp1f + row * 128) + (tid & 1) * 8;
      float4* d = (float4*)(w1 + row * 136) + (tid & 1) * 8;
#pragma unroll
      for (int i = 0; i < 8; i++) d[i] = s[i];
    } else if (tid < 192) {
      int t2 = tid - 128;
      int row = t2 >> 1;
      const float4* s = (const float4*)(Wp2f + row * 64) + (t2 & 1) * 4;
      float4* d = (float4*)(w2 + row * 72) + (t2 & 1) * 4;
#pragma unroll
      for (int i = 0; i < 4; i++) d[i] = s[i];
    }
  }
  __syncthreads();
  int w = tid >> 6, lane = tid & 63, l15 = lane & 15, q = lane >> 4;
  {
    h8 bf[4];
#pragma unroll
    for (int ks = 0; ks < 4; ks++)
      bf[ks] = *(const h8*)(w1 + (16 * w + l15) * 136 + 32 * ks + 8 * q);
    float bv = bp1[16 * w + l15];
#pragma unroll
    for (int mt = 0; mt < 8; mt++) {
      f4 acc = (f4){bv, bv, bv, bv};
#pragma unroll
      for (int ks = 0; ks < 4; ks++) {
        h8 a = *(const h8*)(hl + (16 * mt + l15) * 136 + 32 * ks + 8 * q);
        acc = __builtin_amdgcn_mfma_f32_16x16x32_f16(a, bf[ks], acc, 0, 0, 0);
      }
#pragma unroll
      for (int r = 0; r < 4; r++) {
        float v = acc[r] > 0.f ? acc[r] : 0.f;
        pl[(16 * mt + 4 * q + r) * 72 + 16 * w + l15] = (f16)v;
      }
    }
  }
  __syncthreads();
  {
    int nt = w & 1;
    int o = 16 * nt + l15;
    h8 bf2[2];
#pragma unroll
    for (int ks = 0; ks < 2; ks++)
      bf2[ks] = *(const h8*)(w2 + o * 72 + 32 * ks + 8 * q);
    float bv = (o < 22) ? bp2[o] : 0.f;
#pragma unroll
    for (int mi = 0; mi < 4; mi++) {
      int mt = (w >> 1) * 4 + mi;
      f4 acc = (f4){bv, bv, bv, bv};
#pragma unroll
      for (int ks = 0; ks < 2; ks++) {
        h8 a = *(const h8*)(pl + (16 * mt + l15) * 72 + 32 * ks + 8 * q);
        acc = __builtin_amdgcn_mfma_f32_16x16x32_f16(a, bf2[ks], acc, 0, 0, 0);
      }
      if (o < 22) {
#pragma unroll
        for (int r = 0; r < 4; r++) {
          int brow = bs * 128 + 16 * mt + 4 * q + r;
          out[((long long)brow * NT + (t0 + t)) * 22 + o] = acc[r];
        }
      }
    }
  }
}

extern "C" void kernel_launch(void* const* d_in, const int* in_sizes, int n_in,
                              void* d_out, int out_size, void* d_ws, size_t ws_size,
                              hipStream_t stream) {
  const float* x    = (const float*)d_in[0];
  const float* gam  = (const float*)d_in[1];
  const float* bet  = (const float*)d_in[2];
  const float* Wih0 = (const float*)d_in[3];
  const float* Whh0 = (const float*)d_in[4];
  const float* b0   = (const float*)d_in[5];
  const float* Wih1 = (const float*)d_in[6];
  const float* Whh1 = (const float*)d_in[7];
  const float* b1   = (const float*)d_in[8];
  const float* Wp1  = (const float*)d_in[9];
  const float* bp1  = (const float*)d_in[10];
  const float* Wp2  = (const float*)d_in[11];
  const float* bp2  = (const float*)d_in[12];
  float* out = (float*)d_out;

  uintptr_t base = (uintptr_t)d_ws;
  uintptr_t cur = base;
  auto alloc = [&](size_t bytes) { uintptr_t p = cur; cur += (bytes + 255) & ~(size_t)255; return (void*)p; };
  f16* Wih0f = (f16*)alloc((size_t)512 * 160 * 2);
  f16* Wih1f = (f16*)alloc((size_t)512 * 128 * 2);
  f16* Whh0f = (f16*)alloc((size_t)512 * 136 * 2);
  f16* Whh1f = (f16*)alloc((size_t)512 * 136 * 2);
  f16* Wp1f  = (f16*)alloc((size_t)64 * 128 * 2);
  f16* Wp2f  = (f16*)alloc((size_t)32 * 64 * 2);
  float* ch0 = (float*)alloc((size_t)1024 * 128 * 4);
  float* cc0 = (float*)alloc((size_t)1024 * 128 * 4);
  float* ch1 = (float*)alloc((size_t)1024 * 128 * 4);
  float* cc1 = (float*)alloc((size_t)1024 * 128 * 4);
  size_t fixed = cur - base;
  const size_t per_t = (size_t)1024 * 160 * 2 + (size_t)1024 * 512 * 2 + (size_t)128 * 1024 * 2;
  int tc = 1;
  const int cands[] = {250, 125, 50, 25, 10, 5, 2, 1};
  for (int cd : cands) {
    if (fixed + per_t * (size_t)cd + 4096 <= ws_size) { tc = cd; break; }
  }
  f16* xn  = (f16*)alloc((size_t)1024 * tc * 160 * 2);
  f16* xg  = (f16*)alloc((size_t)tc * 1024 * 512 * 2);
  f16* hsq = (f16*)alloc((size_t)tc * 128 * 1024 * 2);

  int lds1 = 2 * 128 * 168 * 2;   // k_gates<160,*>
  int lds3 = 2 * 128 * 136 * 2;   // k_gates<128,*>
  int lds5 = (128 * 136 + 64 * 136 + 32 * 72 + 128 * 72) * 2;
  hipFuncSetAttribute(reinterpret_cast<const void*>(&k_gates<160, false>),
                      hipFuncAttributeMaxDynamicSharedMemorySize, lds1);
  hipFuncSetAttribute(reinterpret_cast<const void*>(&k_gates<128, true>),
                      hipFuncAttributeMaxDynamicSharedMemorySize, lds3);
  hipFuncSetAttribute(reinterpret_cast<const void*>(&k_proj),
                      hipFuncAttributeMaxDynamicSharedMemorySize, lds5);

  // weight prep
  {
    struct Job { const float* s; f16* d; int sr, sc, dc, tot; };
    Job jobs[6] = {
        {Wih0, Wih0f, 512, 158, 160, 512 * 160},
        {Wih1, Wih1f, 512, 128, 128, 512 * 128},
        {Whh0, Whh0f, 512, 128, 136, 512 * 136},
        {Whh1, Whh1f, 512, 128, 136, 512 * 136},
        {Wp1,  Wp1f,  64, 128, 128, 64 * 128},
        {Wp2,  Wp2f,  22, 64, 64, 32 * 64},
    };
    for (int i = 0; i < 6; i++) {
      int g = (jobs[i].tot + 255) / 256;
      k_prep<<<g, 256, 0, stream>>>(jobs[i].s, jobs[i].d, jobs[i].sr, jobs[i].sc, jobs[i].dc, jobs[i].tot);
    }
  }

  int nch = NT / tc;
  for (int cidx = 0; cidx < nch; cidx++) {
    int t0 = cidx * tc;
    int first = (cidx == 0) ? 1 : 0;
    k_ln<<<dim3(1024 * tc / 32), 256, 0, stream>>>(x, gam, bet, xn, t0, tc);
    k_gates<160, false><<<dim3(tc, 4, 8), 256, lds1, stream>>>(xn, Wih0f, b0, xg, tc);
    k_lstm<<<dim3(64), 512, 0, stream>>>(xg, Whh0f, hsq, ch0, cc0, tc, first);
    k_gates<128, true><<<dim3(tc, 4, 8), 256, lds3, stream>>>(hsq, Wih1f, b1, xg, tc);
    k_lstm<<<dim3(64), 512, 0, stream>>>(xg, Whh1f, hsq, ch1, cc1, tc, first);
    k_proj<<<dim3(tc, 8), 256, lds5, stream>>>(hsq, Wp1f, Wp2f, bp1, bp2, out, tc, t0);
  }
}

// Round 2
// 1587.187 us; speedup vs baseline: 1.1648x; 1.1648x over previous
//
#include <hip/hip_runtime.h>
#include <cstdint>

typedef _Float16 f16;
typedef _Float16 h8 __attribute__((ext_vector_type(8)));
typedef _Float16 h4 __attribute__((ext_vector_type(4)));
typedef float f4 __attribute__((ext_vector_type(4)));

#define NB 1024
#define NT 250
#define IND 158
#define KP0 160
#define NH 128
#define NG 512
#define LN_EPS 1e-5f

__device__ __forceinline__ float fast_sigmoid(float x) {
  float e = __builtin_amdgcn_exp2f(-1.44269504f * x);
  return __builtin_amdgcn_rcpf(1.f + e);
}
__device__ __forceinline__ float fast_tanh(float x) {
  float e = __builtin_amdgcn_exp2f(2.88539008f * x);
  return 1.f - 2.f * __builtin_amdgcn_rcpf(e + 1.f);
}

// ---------------- K0: weight fp32 -> f16 with padding/zero-fill ----------------
__global__ __launch_bounds__(256) void k_prep(const float* __restrict__ src, f16* __restrict__ dst,
                                              int srows, int scols, int dcols, int total) {
  int i = blockIdx.x * 256 + threadIdx.x;
  if (i >= total) return;
  int r = i / dcols, c = i - r * dcols;
  float v = (r < srows && c < scols) ? src[r * scols + c] : 0.f;
  dst[i] = (f16)v;
}

// ---------------- LayerNorm -> xn f16 [B][tc][160] ----------------
__global__ __launch_bounds__(256) void k_ln(const float* __restrict__ x, const float* __restrict__ gamma,
                                            const float* __restrict__ beta, f16* __restrict__ xn,
                                            int t0, int tc) {
  int tid = threadIdx.x;
  int sub = tid & 7;            // 8 threads per row
  int rloc = tid >> 3;          // 32 rows per block
  long long rowi = (long long)blockIdx.x * 32 + rloc;   // row over [B][tc]
  int b = (int)(rowi / tc), t = (int)(rowi % tc);
  const float* xr = x + ((long long)b * NT + (t0 + t)) * IND;
  float vals[20];
  float s = 0.f, ss = 0.f;
#pragma unroll
  for (int i = 0; i < 20; i++) {
    int k = sub + 8 * i;
    float v = (k < IND) ? xr[k] : 0.f;
    vals[i] = v; s += v; ss += v * v;
  }
  s += __shfl_xor(s, 1); ss += __shfl_xor(ss, 1);
  s += __shfl_xor(s, 2); ss += __shfl_xor(ss, 2);
  s += __shfl_xor(s, 4); ss += __shfl_xor(ss, 4);
  float mu = s * (1.f / IND);
  float var = ss * (1.f / IND) - mu * mu;
  float rs = rsqrtf(var + LN_EPS);
  f16* outr = xn + ((long long)b * tc + t) * KP0;
#pragma unroll
  for (int i = 0; i < 20; i++) {
    int k = sub + 8 * i;
    float v = (k < IND) ? (vals[i] - mu) * rs * gamma[k] + beta[k] : 0.f;
    outr[k] = (f16)v;   // k in [0,160): zero-fills K-pad
  }
}

// ---------------- xg = inp @ W^T + bias  (MFMA f16, W rows as M, samples as N) ----------------
// inp rows along K (row-major, rowStride elements); W: [512][KP] f16
// xg out: [tc][1024][512] f16, written as h4 (gate dim contiguous)
template <int KP>
__global__ __launch_bounds__(256, 1) void k_gates(const f16* __restrict__ inp, long long tStride,
                                                  long long rowStride, const f16* __restrict__ W,
                                                  const float* __restrict__ bias, f16* __restrict__ xg) {
  constexpr int KPP = KP + 8;      // pad: row stride multiple of 16B
  constexpr int KS = KP / 32;
  extern __shared__ f16 lds[];
  f16* Wl = lds;                   // [128][KPP]  W rows (M = gates)
  f16* Il = lds + 128 * KPP;       // [128][KPP]  input rows (N = samples)
  int t = blockIdx.x, gs = blockIdx.y, bs = blockIdx.z;
  int tid = threadIdx.x;
  {
    int row = tid >> 1, half = tid & 1;
    const float4* srcw = (const float4*)(W + (gs * 128 + row) * KP) + half * (KP / 16);
    float4* dstw = (float4*)(Wl + row * KPP) + half * (KP / 16);
#pragma unroll
    for (int i = 0; i < KP / 16; i++) dstw[i] = srcw[i];
    const float4* srci = (const float4*)(inp + (long long)t * tStride + (long long)(bs * 128 + row) * rowStride) + half * (KP / 16);
    float4* dsti = (float4*)(Il + row * KPP) + half * (KP / 16);
#pragma unroll
    for (int i = 0; i < KP / 16; i++) dsti[i] = srci[i];
  }
  __syncthreads();
  int w = tid >> 6, lane = tid & 63, l15 = lane & 15, q = lane >> 4;
  // B-fragments: wave w owns sample n-tiles {2w, 2w+1}
  h8 bf[2][KS];
#pragma unroll
  for (int nt = 0; nt < 2; nt++)
#pragma unroll
    for (int ks = 0; ks < KS; ks++)
      bf[nt][ks] = *(const h8*)(Il + (32 * w + 16 * nt + l15) * KPP + 32 * ks + 8 * q);
  f4 acc[8][2];
#pragma unroll
  for (int mt = 0; mt < 8; mt++) {
    float4 b4 = *(const float4*)(bias + gs * 128 + 16 * mt + 4 * q);
#pragma unroll
    for (int nt = 0; nt < 2; nt++) acc[mt][nt] = (f4){b4.x, b4.y, b4.z, b4.w};
  }
#pragma unroll
  for (int mt = 0; mt < 8; mt++) {
    h8 af[KS];
#pragma unroll
    for (int ks = 0; ks < KS; ks++)
      af[ks] = *(const h8*)(Wl + (16 * mt + l15) * KPP + 32 * ks + 8 * q);
#pragma unroll
    for (int nt = 0; nt < 2; nt++)
#pragma unroll
      for (int ks = 0; ks < KS; ks++)
        acc[mt][nt] = __builtin_amdgcn_mfma_f32_16x16x32_f16(af[ks], bf[nt][ks], acc[mt][nt], 0, 0, 0);
  }
  // C: row = gate (16mt + 4q + r, r contiguous), col = sample -> one h4 (8B) store per tile
#pragma unroll
  for (int mt = 0; mt < 8; mt++)
#pragma unroll
    for (int nt = 0; nt < 2; nt++) {
      h4 o4;
#pragma unroll
      for (int r = 0; r < 4; r++) o4[r] = (f16)acc[mt][nt][r];
      long long sample = bs * 128 + 32 * w + 16 * nt + l15;
      *(h4*)(xg + ((long long)t * NB + sample) * NG + gs * 128 + 16 * mt + 4 * q) = o4;
    }
}

// ---------------- LSTM recurrence (persistent over chunk) ----------------
// xg: [tc][1024][512] f16; Whh: [512][136] f16 (padded); hseq out: [tc][1024][128] f16
__global__ __launch_bounds__(512, 2) void k_lstm(const f16* __restrict__ xg, const f16* __restrict__ Whh,
                                                 f16* __restrict__ hseq, float* __restrict__ carry_h,
                                                 float* __restrict__ carry_c, int tc, int first) {
  __shared__ f16 hbuf[2][16][136];
  int tid = threadIdx.x;
  int w = tid >> 6, lane = tid & 63, l15 = lane & 15, q = lane >> 4;
  int b0 = blockIdx.x * 16;
  for (int i = tid; i < 2176; i += 512) {
    int n = i / 136, k = i - n * 136;
    float hv = (!first && k < NH) ? carry_h[(b0 + n) * NH + k] : 0.f;
    hbuf[0][n][k] = (f16)hv;
  }
  int jbase = 16 * w + 4 * q;     // this lane's hidden-unit base (C-layout row)
  float c[4];
#pragma unroll
  for (int r = 0; r < 4; r++)
    c[r] = first ? 0.f : carry_c[(b0 + l15) * NH + jbase + r];
  // W_hh A-fragments: register-resident for the whole chunk (64 VGPRs)
  h8 af[4][4];
#pragma unroll
  for (int g = 0; g < 4; g++)
#pragma unroll
    for (int ks = 0; ks < 4; ks++)
      af[g][ks] = *(const h8*)(Whh + (128 * g + 16 * w + l15) * 136 + 32 * ks + 8 * q);
  __syncthreads();
  const f16* xgb = xg + (long long)(b0 + l15) * NG + jbase;
  const long long tstep = (long long)NB * NG;
  // depth-2 software pipeline on the xg gate loads
  h4 xa[4], xb[4], xc[4];
#pragma unroll
  for (int g = 0; g < 4; g++) xa[g] = *(const h4*)(xgb + 128 * g);
  if (tc > 1) {
#pragma unroll
    for (int g = 0; g < 4; g++) xb[g] = *(const h4*)(xgb + tstep + 128 * g);
  }
  for (int t = 0; t < tc; t++) {
    int p = t & 1;
    if (t + 2 < tc) {
      const f16* xr = xgb + (long long)(t + 2) * tstep;
#pragma unroll
      for (int g = 0; g < 4; g++) xc[g] = *(const h4*)(xr + 128 * g);
    }
    h8 bf[4];
#pragma unroll
    for (int ks = 0; ks < 4; ks++)
      bf[ks] = *(const h8*)(&hbuf[p][l15][32 * ks + 8 * q]);
    f4 acc[4], acc2[4];
#pragma unroll
    for (int g = 0; g < 4; g++) {
#pragma unroll
      for (int r = 0; r < 4; r++) acc[g][r] = (float)xa[g][r];
      acc2[g] = (f4){0.f, 0.f, 0.f, 0.f};
    }
    // split K-chain: 2 accumulators of depth 2 instead of one of depth 4
#pragma unroll
    for (int g = 0; g < 4; g++) {
      acc[g]  = __builtin_amdgcn_mfma_f32_16x16x32_f16(af[g][0], bf[0], acc[g], 0, 0, 0);
      acc2[g] = __builtin_amdgcn_mfma_f32_16x16x32_f16(af[g][2], bf[2], acc2[g], 0, 0, 0);
      acc[g]  = __builtin_amdgcn_mfma_f32_16x16x32_f16(af[g][1], bf[1], acc[g], 0, 0, 0);
      acc2[g] = __builtin_amdgcn_mfma_f32_16x16x32_f16(af[g][3], bf[3], acc2[g], 0, 0, 0);
    }
    h4 hv4;
#pragma unroll
    for (int r = 0; r < 4; r++) {
      float gi = acc[0][r] + acc2[0][r];
      float gf = acc[1][r] + acc2[1][r];
      float gg = acc[2][r] + acc2[2][r];
      float go = acc[3][r] + acc2[3][r];
      float iv = fast_sigmoid(gi);
      float fv = fast_sigmoid(gf);
      float gv = fast_tanh(gg);
      float ov = fast_sigmoid(go);
      float cc = fv * c[r] + iv * gv;
      c[r] = cc;
      float hv = ov * fast_tanh(cc);
      hv4[r] = (f16)hv;
    }
    *(h4*)(&hbuf[1 - p][l15][jbase]) = hv4;
    *(h4*)(hseq + ((long long)t * NB + b0 + l15) * NH + jbase) = hv4;
#pragma unroll
    for (int g = 0; g < 4; g++) { xa[g] = xb[g]; xb[g] = xc[g]; }
    // LDS-only barrier: do NOT drain vmcnt (xg prefetches / hseq stores stay in flight)
    asm volatile("s_waitcnt lgkmcnt(0)\n\ts_barrier" ::: "memory");
  }
#pragma unroll
  for (int r = 0; r < 4; r++)
    carry_c[(b0 + l15) * NH + jbase + r] = c[r];
  int pf = tc & 1;
  for (int i = tid; i < 2048; i += 512) {
    int n = i >> 7, k = i & 127;
    carry_h[(b0 + n) * NH + k] = (float)hbuf[pf][n][k];
  }
}

// ---------------- out = relu(h1 @ Wp1^T + bp1) @ Wp2^T + bp2 ----------------
// hseq: [tc][1024][128] f16 rows
__global__ __launch_bounds__(256, 1) void k_proj(const f16* __restrict__ hseq, const f16* __restrict__ Wp1f,
                                                 const f16* __restrict__ Wp2f, const float* __restrict__ bp1,
                                                 const float* __restrict__ bp2, float* __restrict__ out,
                                                 int tc, int t0) {
  extern __shared__ f16 lds[];
  f16* hl = lds;                  // [128][136]
  f16* w1 = hl + 128 * 136;       // [64][136]
  f16* w2 = w1 + 64 * 136;        // [32][72]
  f16* pl = w2 + 32 * 72;         // [128][72]
  int t = blockIdx.x, bs = blockIdx.y;
  int tid = threadIdx.x;
  {
    int b = tid >> 1, half = tid & 1;
    const float4* s = (const float4*)(hseq + ((long long)t * NB + bs * 128 + b) * NH) + half * 8;
    float4* d = (float4*)(hl + b * 136) + half * 8;
#pragma unroll
    for (int i = 0; i < 8; i++) d[i] = s[i];
    if (tid < 128) {
      int row = tid >> 1;
      const float4* sw = (const float4*)(Wp1f + row * 128) + (tid & 1) * 8;
      float4* dw = (float4*)(w1 + row * 136) + (tid & 1) * 8;
#pragma unroll
      for (int i = 0; i < 8; i++) dw[i] = sw[i];
    } else if (tid < 192) {
      int t2 = tid - 128;
      int row = t2 >> 1;
      const float4* sw = (const float4*)(Wp2f + row * 64) + (t2 & 1) * 4;
      float4* dw = (float4*)(w2 + row * 72) + (t2 & 1) * 4;
#pragma unroll
      for (int i = 0; i < 4; i++) dw[i] = sw[i];
    }
  }
  __syncthreads();
  int w = tid >> 6, lane = tid & 63, l15 = lane & 15, q = lane >> 4;
  {
    h8 bf[4];
#pragma unroll
    for (int ks = 0; ks < 4; ks++)
      bf[ks] = *(const h8*)(w1 + (16 * w + l15) * 136 + 32 * ks + 8 * q);
    float bv = bp1[16 * w + l15];
#pragma unroll
    for (int mt = 0; mt < 8; mt++) {
      f4 acc = (f4){bv, bv, bv, bv};
#pragma unroll
      for (int ks = 0; ks < 4; ks++) {
        h8 a = *(const h8*)(hl + (16 * mt + l15) * 136 + 32 * ks + 8 * q);
        acc = __builtin_amdgcn_mfma_f32_16x16x32_f16(a, bf[ks], acc, 0, 0, 0);
      }
#pragma unroll
      for (int r = 0; r < 4; r++) {
        float v = acc[r] > 0.f ? acc[r] : 0.f;
        pl[(16 * mt + 4 * q + r) * 72 + 16 * w + l15] = (f16)v;
      }
    }
  }
  __syncthreads();
  {
    int nt = w & 1;
    int o = 16 * nt + l15;
    h8 bf2[2];
#pragma unroll
    for (int ks = 0; ks < 2; ks++)
      bf2[ks] = *(const h8*)(w2 + o * 72 + 32 * ks + 8 * q);
    float bv = (o < 22) ? bp2[o] : 0.f;
#pragma unroll
    for (int mi = 0; mi < 4; mi++) {
      int mt = (w >> 1) * 4 + mi;
      f4 acc = (f4){bv, bv, bv, bv};
#pragma unroll
      for (int ks = 0; ks < 2; ks++) {
        h8 a = *(const h8*)(pl + (16 * mt + l15) * 72 + 32 * ks + 8 * q);
        acc = __builtin_amdgcn_mfma_f32_16x16x32_f16(a, bf2[ks], acc, 0, 0, 0);
      }
      if (o < 22) {
#pragma unroll
        for (int r = 0; r < 4; r++) {
          int brow = bs * 128 + 16 * mt + 4 * q + r;
          out[((long long)brow * NT + (t0 + t)) * 22 + o] = acc[r];
        }
      }
    }
  }
}

extern "C" void kernel_launch(void* const* d_in, const int* in_sizes, int n_in,
                              void* d_out, int out_size, void* d_ws, size_t ws_size,
                              hipStream_t stream) {
  const float* x    = (const float*)d_in[0];
  const float* gam  = (const float*)d_in[1];
  const float* bet  = (const float*)d_in[2];
  const float* Wih0 = (const float*)d_in[3];
  const float* Whh0 = (const float*)d_in[4];
  const float* b0   = (const float*)d_in[5];
  const float* Wih1 = (const float*)d_in[6];
  const float* Whh1 = (const float*)d_in[7];
  const float* b1   = (const float*)d_in[8];
  const float* Wp1  = (const float*)d_in[9];
  const float* bp1  = (const float*)d_in[10];
  const float* Wp2  = (const float*)d_in[11];
  const float* bp2  = (const float*)d_in[12];
  float* out = (float*)d_out;

  uintptr_t base = (uintptr_t)d_ws;
  uintptr_t cur = base;
  auto alloc = [&](size_t bytes) { uintptr_t p = cur; cur += (bytes + 255) & ~(size_t)255; return (void*)p; };
  f16* Wih0f = (f16*)alloc((size_t)512 * 160 * 2);
  f16* Wih1f = (f16*)alloc((size_t)512 * 128 * 2);
  f16* Whh0f = (f16*)alloc((size_t)512 * 136 * 2);
  f16* Whh1f = (f16*)alloc((size_t)512 * 136 * 2);
  f16* Wp1f  = (f16*)alloc((size_t)64 * 128 * 2);
  f16* Wp2f  = (f16*)alloc((size_t)32 * 64 * 2);
  float* ch0 = (float*)alloc((size_t)1024 * 128 * 4);
  float* cc0 = (float*)alloc((size_t)1024 * 128 * 4);
  float* ch1 = (float*)alloc((size_t)1024 * 128 * 4);
  float* cc1 = (float*)alloc((size_t)1024 * 128 * 4);
  size_t fixed = cur - base;
  const size_t per_t = (size_t)1024 * 160 * 2 + (size_t)1024 * 512 * 2 + (size_t)1024 * 128 * 2;
  int tc = 1;
  const int cands[] = {250, 125, 50, 25, 10, 5, 2, 1};
  for (int cd : cands) {
    if (fixed + per_t * (size_t)cd + 4096 <= ws_size) { tc = cd; break; }
  }
  f16* xn  = (f16*)alloc((size_t)1024 * tc * 160 * 2);
  f16* xg  = (f16*)alloc((size_t)tc * 1024 * 512 * 2);
  f16* hsq = (f16*)alloc((size_t)tc * 1024 * 128 * 2);

  int lds1 = 2 * 128 * 168 * 2;   // k_gates<160>
  int lds3 = 2 * 128 * 136 * 2;   // k_gates<128>
  int lds5 = (128 * 136 + 64 * 136 + 32 * 72 + 128 * 72) * 2;
  hipFuncSetAttribute(reinterpret_cast<const void*>(&k_gates<160>),
                      hipFuncAttributeMaxDynamicSharedMemorySize, lds1);
  hipFuncSetAttribute(reinterpret_cast<const void*>(&k_gates<128>),
                      hipFuncAttributeMaxDynamicSharedMemorySize, lds3);
  hipFuncSetAttribute(reinterpret_cast<const void*>(&k_proj),
                      hipFuncAttributeMaxDynamicSharedMemorySize, lds5);

  // weight prep
  {
    struct Job { const float* s; f16* d; int sr, sc, dc, tot; };
    Job jobs[6] = {
        {Wih0, Wih0f, 512, 158, 160, 512 * 160},
        {Wih1, Wih1f, 512, 128, 128, 512 * 128},
        {Whh0, Whh0f, 512, 128, 136, 512 * 136},
        {Whh1, Whh1f, 512, 128, 136, 512 * 136},
        {Wp1,  Wp1f,  64, 128, 128, 64 * 128},
        {Wp2,  Wp2f,  22, 64, 64, 32 * 64},
    };
    for (int i = 0; i < 6; i++) {
      int g = (jobs[i].tot + 255) / 256;
      k_prep<<<g, 256, 0, stream>>>(jobs[i].s, jobs[i].d, jobs[i].sr, jobs[i].sc, jobs[i].dc, jobs[i].tot);
    }
  }

  int nch = NT / tc;
  for (int cidx = 0; cidx < nch; cidx++) {
    int t0 = cidx * tc;
    int first = (cidx == 0) ? 1 : 0;
    k_ln<<<dim3(1024 * tc / 32), 256, 0, stream>>>(x, gam, bet, xn, t0, tc);
    k_gates<160><<<dim3(tc, 4, 8), 256, lds1, stream>>>(xn, 160, (long long)tc * 160, Wih0f, b0, xg);
    k_lstm<<<dim3(64), 512, 0, stream>>>(xg, Whh0f, hsq, ch0, cc0, tc, first);
    k_gates<128><<<dim3(tc, 4, 8), 256, lds3, stream>>>(hsq, (long long)NB * 128, 128, Wih1f, b1, xg);
    k_lstm<<<dim3(64), 512, 0, stream>>>(xg, Whh1f, hsq, ch1, cc1, tc, first);
    k_proj<<<dim3(tc, 8), 256, lds5, stream>>>(hsq, Wp1f, Wp2f, bp1, bp2, out, tc, t0);
  }
}

// Round 3
// 1052.021 us; speedup vs baseline: 1.7574x; 1.5087x over previous
//
#include <hip/hip_runtime.h>
#include <cstdint>

typedef _Float16 f16;
typedef _Float16 h8 __attribute__((ext_vector_type(8)));
typedef _Float16 h4 __attribute__((ext_vector_type(4)));
typedef float f4 __attribute__((ext_vector_type(4)));

#define NB 1024
#define NT 250
#define IND 158
#define KP0 160
#define NH 128
#define NG 512
#define LN_EPS 1e-5f

__device__ __forceinline__ float fast_sigmoid(float x) {
  float e = __builtin_amdgcn_exp2f(-1.44269504f * x);
  return __builtin_amdgcn_rcpf(1.f + e);
}
__device__ __forceinline__ float fast_tanh(float x) {
  float e = __builtin_amdgcn_exp2f(2.88539008f * x);
  return 1.f - 2.f * __builtin_amdgcn_rcpf(e + 1.f);
}

// ---------------- K0: weight fp32 -> f16 with padding/zero-fill ----------------
__global__ __launch_bounds__(256) void k_prep(const float* __restrict__ src, f16* __restrict__ dst,
                                              int srows, int scols, int dcols, int total) {
  int i = blockIdx.x * 256 + threadIdx.x;
  if (i >= total) return;
  int r = i / dcols, c = i - r * dcols;
  float v = (r < srows && c < scols) ? src[r * scols + c] : 0.f;
  dst[i] = (f16)v;
}

// ---------------- LayerNorm -> xn f16 [B][tc][160] ----------------
__global__ __launch_bounds__(256) void k_ln(const float* __restrict__ x, const float* __restrict__ gamma,
                                            const float* __restrict__ beta, f16* __restrict__ xn,
                                            int t0, int tc) {
  int tid = threadIdx.x;
  int sub = tid & 7;            // 8 threads per row
  int rloc = tid >> 3;          // 32 rows per block
  long long rowi = (long long)blockIdx.x * 32 + rloc;   // row over [B][tc]
  int b = (int)(rowi / tc), t = (int)(rowi % tc);
  const float* xr = x + ((long long)b * NT + (t0 + t)) * IND;
  float vals[20];
  float s = 0.f, ss = 0.f;
#pragma unroll
  for (int i = 0; i < 20; i++) {
    int k = sub + 8 * i;
    float v = (k < IND) ? xr[k] : 0.f;
    vals[i] = v; s += v; ss += v * v;
  }
  s += __shfl_xor(s, 1); ss += __shfl_xor(ss, 1);
  s += __shfl_xor(s, 2); ss += __shfl_xor(ss, 2);
  s += __shfl_xor(s, 4); ss += __shfl_xor(ss, 4);
  float mu = s * (1.f / IND);
  float var = ss * (1.f / IND) - mu * mu;
  float rs = rsqrtf(var + LN_EPS);
  f16* outr = xn + ((long long)b * tc + t) * KP0;
#pragma unroll
  for (int i = 0; i < 20; i++) {
    int k = sub + 8 * i;
    float v = (k < IND) ? (vals[i] - mu) * rs * gamma[k] + beta[k] : 0.f;
    outr[k] = (f16)v;   // k in [0,160): zero-fills K-pad
  }
}

// ---------------- xg = inp @ W^T + bias  (MFMA f16, W rows as M, samples as N) ----------------
template <int KP>
__global__ __launch_bounds__(256, 1) void k_gates(const f16* __restrict__ inp, long long tStride,
                                                  long long rowStride, const f16* __restrict__ W,
                                                  const float* __restrict__ bias, f16* __restrict__ xg) {
  constexpr int KPP = KP + 8;      // pad: row stride multiple of 16B
  constexpr int KS = KP / 32;
  extern __shared__ f16 lds[];
  f16* Wl = lds;                   // [128][KPP]  W rows (M = gates)
  f16* Il = lds + 128 * KPP;       // [128][KPP]  input rows (N = samples)
  int t = blockIdx.x, gs = blockIdx.y, bs = blockIdx.z;
  int tid = threadIdx.x;
  {
    int row = tid >> 1, half = tid & 1;
    const float4* srcw = (const float4*)(W + (gs * 128 + row) * KP) + half * (KP / 16);
    float4* dstw = (float4*)(Wl + row * KPP) + half * (KP / 16);
#pragma unroll
    for (int i = 0; i < KP / 16; i++) dstw[i] = srcw[i];
    const float4* srci = (const float4*)(inp + (long long)t * tStride + (long long)(bs * 128 + row) * rowStride) + half * (KP / 16);
    float4* dsti = (float4*)(Il + row * KPP) + half * (KP / 16);
#pragma unroll
    for (int i = 0; i < KP / 16; i++) dsti[i] = srci[i];
  }
  __syncthreads();
  int w = tid >> 6, lane = tid & 63, l15 = lane & 15, q = lane >> 4;
  h8 bf[2][KS];
#pragma unroll
  for (int nt = 0; nt < 2; nt++)
#pragma unroll
    for (int ks = 0; ks < KS; ks++)
      bf[nt][ks] = *(const h8*)(Il + (32 * w + 16 * nt + l15) * KPP + 32 * ks + 8 * q);
  f4 acc[8][2];
#pragma unroll
  for (int mt = 0; mt < 8; mt++) {
    float4 b4 = *(const float4*)(bias + gs * 128 + 16 * mt + 4 * q);
#pragma unroll
    for (int nt = 0; nt < 2; nt++) acc[mt][nt] = (f4){b4.x, b4.y, b4.z, b4.w};
  }
#pragma unroll
  for (int mt = 0; mt < 8; mt++) {
    h8 af[KS];
#pragma unroll
    for (int ks = 0; ks < KS; ks++)
      af[ks] = *(const h8*)(Wl + (16 * mt + l15) * KPP + 32 * ks + 8 * q);
#pragma unroll
    for (int nt = 0; nt < 2; nt++)
#pragma unroll
      for (int ks = 0; ks < KS; ks++)
        acc[mt][nt] = __builtin_amdgcn_mfma_f32_16x16x32_f16(af[ks], bf[nt][ks], acc[mt][nt], 0, 0, 0);
  }
#pragma unroll
  for (int mt = 0; mt < 8; mt++)
#pragma unroll
    for (int nt = 0; nt < 2; nt++) {
      h4 o4;
#pragma unroll
      for (int r = 0; r < 4; r++) o4[r] = (f16)acc[mt][nt][r];
      long long sample = bs * 128 + 32 * w + 16 * nt + l15;
      *(h4*)(xg + ((long long)t * NB + sample) * NG + gs * 128 + 16 * mt + 4 * q) = o4;
    }
}

// ---------------- Fused 2-layer LSTM, pipelined across layers ----------------
// Each wave owns 16 hidden units of BOTH layers for the block's 16 samples.
// Iteration n: layer-0 computes h0(n); layer-1 computes h1(n-1) from h0(n-1), h1(n-2).
// xg: [tc][1024][512] (layer-0 pre-gates incl. b0); Whh0f/Wih1f in registers; Whh1 in LDS.
__global__ __launch_bounds__(512, 2) void k_fused(const f16* __restrict__ xg, const f16* __restrict__ Whh0f,
                                                  const f16* __restrict__ Wih1f, const f16* __restrict__ Whh1f,
                                                  const float* __restrict__ b1, f16* __restrict__ hseq,
                                                  float* __restrict__ ch0, float* __restrict__ cc0,
                                                  float* __restrict__ ch1, float* __restrict__ cc1,
                                                  int tc, int first) {
  extern __shared__ f16 lds[];
  f16* WhhL = lds;                       // [512][136] = 69632 f16
  f16* h0b = lds + 69632;                // [2][16][136] = 4352
  f16* h1b = h0b + 4352;                 // [2][16][136] = 4352
  int tid = threadIdx.x;
  int w = tid >> 6, lane = tid & 63, l15 = lane & 15, q = lane >> 4;
  int b0 = blockIdx.x * 16;
  int jbase = 16 * w + 4 * q;

  // stage Whh1 -> LDS (8B chunks)
  {
    const unsigned long long* ws = (const unsigned long long*)Whh1f;
    unsigned long long* wd = (unsigned long long*)WhhL;
    for (int i = tid; i < 17408; i += 512) wd[i] = ws[i];
  }
  // h-state buffers: h0(-1) -> h0b parity 0; h1(-1) -> h1b parity 1; other parity zeroed
  for (int i = tid; i < 2176; i += 512) {
    int n = i / 136, k = i - n * 136;
    float h0v = (!first && k < NH) ? ch0[(b0 + n) * NH + k] : 0.f;
    float h1v = (!first && k < NH) ? ch1[(b0 + n) * NH + k] : 0.f;
    h0b[i] = (f16)h0v;          // parity 0
    h0b[2176 + i] = (f16)0.f;   // parity 1
    h1b[i] = (f16)0.f;          // parity 0
    h1b[2176 + i] = (f16)h1v;   // parity 1
  }
  float c0r[4], c1r[4];
#pragma unroll
  for (int r = 0; r < 4; r++) {
    c0r[r] = first ? 0.f : cc0[(b0 + l15) * NH + jbase + r];
    c1r[r] = first ? 0.f : cc1[(b0 + l15) * NH + jbase + r];
  }
  // register-resident weight fragments: Whh0 (layer-0) + Wih1 (layer-1 ih part)
  h8 af0[4][4], af1[4][4];
#pragma unroll
  for (int g = 0; g < 4; g++)
#pragma unroll
    for (int ks = 0; ks < 4; ks++) {
      af0[g][ks] = *(const h8*)(Whh0f + (128 * g + 16 * w + l15) * 136 + 32 * ks + 8 * q);
      af1[g][ks] = *(const h8*)(Wih1f + (128 * g + 16 * w + l15) * 128 + 32 * ks + 8 * q);
    }
  f4 bias1[4];
#pragma unroll
  for (int g = 0; g < 4; g++) {
    float4 b4 = *(const float4*)(b1 + 128 * g + jbase);
    bias1[g] = (f4){b4.x, b4.y, b4.z, b4.w};
  }
  __syncthreads();

  const f16* xgb = xg + (long long)(b0 + l15) * NG + jbase;
  const long long tstep = (long long)NB * NG;
  h4 xa[4], xb[4], xc[4];
#pragma unroll
  for (int g = 0; g < 4; g++) xa[g] = *(const h4*)(xgb + 128 * g);
  if (tc > 1) {
#pragma unroll
    for (int g = 0; g < 4; g++) xb[g] = *(const h4*)(xgb + tstep + 128 * g);
  }
  h4 h0last, h1last;
  const int ldsrow = l15 * 136;

  for (int n = 0; n <= tc; n++) {
    int p = n & 1;
    // h0(n-1) fragments — used by layer-0 recurrence AND layer-1 ih-input
    h8 bf0[4];
#pragma unroll
    for (int ks = 0; ks < 4; ks++)
      bf0[ks] = *(const h8*)(h0b + p * 2176 + ldsrow + 32 * ks + 8 * q);
    if (n < tc) {   // ---- layer 0, step t = n ----
      f4 acc[4];
#pragma unroll
      for (int g = 0; g < 4; g++)
#pragma unroll
        for (int r = 0; r < 4; r++) acc[g][r] = (float)xa[g][r];
#pragma unroll
      for (int g = 0; g < 4; g++)
#pragma unroll
        for (int ks = 0; ks < 4; ks++)
          acc[g] = __builtin_amdgcn_mfma_f32_16x16x32_f16(af0[g][ks], bf0[ks], acc[g], 0, 0, 0);
      h4 hv;
#pragma unroll
      for (int r = 0; r < 4; r++) {
        float iv = fast_sigmoid(acc[0][r]);
        float fv = fast_sigmoid(acc[1][r]);
        float gv = fast_tanh(acc[2][r]);
        float ov = fast_sigmoid(acc[3][r]);
        float cc = fv * c0r[r] + iv * gv;
        c0r[r] = cc;
        hv[r] = (f16)(ov * fast_tanh(cc));
      }
      *(h4*)(h0b + (1 - p) * 2176 + ldsrow + jbase) = hv;
      h0last = hv;
    }
    if (n >= 1) {   // ---- layer 1, step t = n-1 ----
      h8 bf1[4];
#pragma unroll
      for (int ks = 0; ks < 4; ks++)
        bf1[ks] = *(const h8*)(h1b + p * 2176 + ldsrow + 32 * ks + 8 * q);
      f4 acc[4];
#pragma unroll
      for (int g = 0; g < 4; g++) acc[g] = bias1[g];
#pragma unroll
      for (int g = 0; g < 4; g++)
#pragma unroll
        for (int ks = 0; ks < 4; ks++)
          acc[g] = __builtin_amdgcn_mfma_f32_16x16x32_f16(af1[g][ks], bf0[ks], acc[g], 0, 0, 0);
#pragma unroll
      for (int g = 0; g < 4; g++)
#pragma unroll
        for (int ks = 0; ks < 4; ks++) {
          h8 aw = *(const h8*)(WhhL + (128 * g + 16 * w + l15) * 136 + 32 * ks + 8 * q);
          acc[g] = __builtin_amdgcn_mfma_f32_16x16x32_f16(aw, bf1[ks], acc[g], 0, 0, 0);
        }
      h4 hv;
#pragma unroll
      for (int r = 0; r < 4; r++) {
        float iv = fast_sigmoid(acc[0][r]);
        float fv = fast_sigmoid(acc[1][r]);
        float gv = fast_tanh(acc[2][r]);
        float ov = fast_sigmoid(acc[3][r]);
        float cc = fv * c1r[r] + iv * gv;
        c1r[r] = cc;
        hv[r] = (f16)(ov * fast_tanh(cc));
      }
      *(h4*)(h1b + (1 - p) * 2176 + ldsrow + jbase) = hv;
      *(h4*)(hseq + ((long long)(n - 1) * NB + b0 + l15) * NH + jbase) = hv;
      h1last = hv;
    }
    if (n + 2 < tc) {
      const f16* xr = xgb + (long long)(n + 2) * tstep;
#pragma unroll
      for (int g = 0; g < 4; g++) xc[g] = *(const h4*)(xr + 128 * g);
    }
#pragma unroll
    for (int g = 0; g < 4; g++) { xa[g] = xb[g]; xb[g] = xc[g]; }
    // LDS-only barrier: xg prefetches / hseq stores stay in flight
    asm volatile("s_waitcnt lgkmcnt(0)\n\ts_barrier" ::: "memory");
  }
#pragma unroll
  for (int r = 0; r < 4; r++) {
    int idx = (b0 + l15) * NH + jbase + r;
    cc0[idx] = c0r[r];
    cc1[idx] = c1r[r];
    ch0[idx] = (float)h0last[r];
    ch1[idx] = (float)h1last[r];
  }
}

// ---------------- out = relu(h1 @ Wp1^T + bp1) @ Wp2^T + bp2 ----------------
__global__ __launch_bounds__(256, 1) void k_proj(const f16* __restrict__ hseq, const f16* __restrict__ Wp1f,
                                                 const f16* __restrict__ Wp2f, const float* __restrict__ bp1,
                                                 const float* __restrict__ bp2, float* __restrict__ out,
                                                 int tc, int t0) {
  extern __shared__ f16 lds[];
  f16* hl = lds;                  // [128][136]
  f16* w1 = hl + 128 * 136;       // [64][136]
  f16* w2 = w1 + 64 * 136;        // [32][72]
  f16* pl = w2 + 32 * 72;         // [128][72]
  int t = blockIdx.x, bs = blockIdx.y;
  int tid = threadIdx.x;
  {
    int b = tid >> 1, half = tid & 1;
    const float4* s = (const float4*)(hseq + ((long long)t * NB + bs * 128 + b) * NH) + half * 8;
    float4* d = (float4*)(hl + b * 136) + half * 8;
#pragma unroll
    for (int i = 0; i < 8; i++) d[i] = s[i];
    if (tid < 128) {
      int row = tid >> 1;
      const float4* sw = (const float4*)(Wp1f + row * 128) + (tid & 1) * 8;
      float4* dw = (float4*)(w1 + row * 136) + (tid & 1) * 8;
#pragma unroll
      for (int i = 0; i < 8; i++) dw[i] = sw[i];
    } else if (tid < 192) {
      int t2 = tid - 128;
      int row = t2 >> 1;
      const float4* sw = (const float4*)(Wp2f + row * 64) + (t2 & 1) * 4;
      float4* dw = (float4*)(w2 + row * 72) + (t2 & 1) * 4;
#pragma unroll
      for (int i = 0; i < 4; i++) dw[i] = sw[i];
    }
  }
  __syncthreads();
  int w = tid >> 6, lane = tid & 63, l15 = lane & 15, q = lane >> 4;
  {
    h8 bf[4];
#pragma unroll
    for (int ks = 0; ks < 4; ks++)
      bf[ks] = *(const h8*)(w1 + (16 * w + l15) * 136 + 32 * ks + 8 * q);
    float bv = bp1[16 * w + l15];
#pragma unroll
    for (int mt = 0; mt < 8; mt++) {
      f4 acc = (f4){bv, bv, bv, bv};
#pragma unroll
      for (int ks = 0; ks < 4; ks++) {
        h8 a = *(const h8*)(hl + (16 * mt + l15) * 136 + 32 * ks + 8 * q);
        acc = __builtin_amdgcn_mfma_f32_16x16x32_f16(a, bf[ks], acc, 0, 0, 0);
      }
#pragma unroll
      for (int r = 0; r < 4; r++) {
        float v = acc[r] > 0.f ? acc[r] : 0.f;
        pl[(16 * mt + 4 * q + r) * 72 + 16 * w + l15] = (f16)v;
      }
    }
  }
  __syncthreads();
  {
    int nt = w & 1;
    int o = 16 * nt + l15;
    h8 bf2[2];
#pragma unroll
    for (int ks = 0; ks < 2; ks++)
      bf2[ks] = *(const h8*)(w2 + o * 72 + 32 * ks + 8 * q);
    float bv = (o < 22) ? bp2[o] : 0.f;
#pragma unroll
    for (int mi = 0; mi < 4; mi++) {
      int mt = (w >> 1) * 4 + mi;
      f4 acc = (f4){bv, bv, bv, bv};
#pragma unroll
      for (int ks = 0; ks < 2; ks++) {
        h8 a = *(const h8*)(pl + (16 * mt + l15) * 72 + 32 * ks + 8 * q);
        acc = __builtin_amdgcn_mfma_f32_16x16x32_f16(a, bf2[ks], acc, 0, 0, 0);
      }
      if (o < 22) {
#pragma unroll
        for (int r = 0; r < 4; r++) {
          int brow = bs * 128 + 16 * mt + 4 * q + r;
          out[((long long)brow * NT + (t0 + t)) * 22 + o] = acc[r];
        }
      }
    }
  }
}

extern "C" void kernel_launch(void* const* d_in, const int* in_sizes, int n_in,
                              void* d_out, int out_size, void* d_ws, size_t ws_size,
                              hipStream_t stream) {
  const float* x    = (const float*)d_in[0];
  const float* gam  = (const float*)d_in[1];
  const float* bet  = (const float*)d_in[2];
  const float* Wih0 = (const float*)d_in[3];
  const float* Whh0 = (const float*)d_in[4];
  const float* b0   = (const float*)d_in[5];
  const float* Wih1 = (const float*)d_in[6];
  const float* Whh1 = (const float*)d_in[7];
  const float* b1   = (const float*)d_in[8];
  const float* Wp1  = (const float*)d_in[9];
  const float* bp1  = (const float*)d_in[10];
  const float* Wp2  = (const float*)d_in[11];
  const float* bp2  = (const float*)d_in[12];
  float* out = (float*)d_out;

  uintptr_t base = (uintptr_t)d_ws;
  uintptr_t cur = base;
  auto alloc = [&](size_t bytes) { uintptr_t p = cur; cur += (bytes + 255) & ~(size_t)255; return (void*)p; };
  f16* Wih0f = (f16*)alloc((size_t)512 * 160 * 2);
  f16* Wih1f = (f16*)alloc((size_t)512 * 128 * 2);
  f16* Whh0f = (f16*)alloc((size_t)512 * 136 * 2);
  f16* Whh1f = (f16*)alloc((size_t)512 * 136 * 2);
  f16* Wp1f  = (f16*)alloc((size_t)64 * 128 * 2);
  f16* Wp2f  = (f16*)alloc((size_t)32 * 64 * 2);
  float* ch0 = (float*)alloc((size_t)1024 * 128 * 4);
  float* cc0 = (float*)alloc((size_t)1024 * 128 * 4);
  float* ch1 = (float*)alloc((size_t)1024 * 128 * 4);
  float* cc1 = (float*)alloc((size_t)1024 * 128 * 4);
  size_t fixed = cur - base;
  const size_t per_t = (size_t)1024 * 160 * 2 + (size_t)1024 * 512 * 2 + (size_t)1024 * 128 * 2;
  int tc = 1;
  const int cands[] = {250, 125, 50, 25, 10, 5, 2, 1};
  for (int cd : cands) {
    if (fixed + per_t * (size_t)cd + 4096 <= ws_size) { tc = cd; break; }
  }
  f16* xn  = (f16*)alloc((size_t)1024 * tc * 160 * 2);
  f16* xg  = (f16*)alloc((size_t)tc * 1024 * 512 * 2);
  f16* hsq = (f16*)alloc((size_t)tc * 1024 * 128 * 2);

  int lds1 = 2 * 128 * 168 * 2;                                // k_gates<160>
  int ldsF = (69632 + 4352 + 4352) * 2;                        // k_fused = 156672 B
  int lds5 = (128 * 136 + 64 * 136 + 32 * 72 + 128 * 72) * 2;  // k_proj
  hipFuncSetAttribute(reinterpret_cast<const void*>(&k_gates<160>),
                      hipFuncAttributeMaxDynamicSharedMemorySize, lds1);
  hipFuncSetAttribute(reinterpret_cast<const void*>(&k_fused),
                      hipFuncAttributeMaxDynamicSharedMemorySize, ldsF);
  hipFuncSetAttribute(reinterpret_cast<const void*>(&k_proj),
                      hipFuncAttributeMaxDynamicSharedMemorySize, lds5);

  // weight prep
  {
    struct Job { const float* s; f16* d; int sr, sc, dc, tot; };
    Job jobs[6] = {
        {Wih0, Wih0f, 512, 158, 160, 512 * 160},
        {Wih1, Wih1f, 512, 128, 128, 512 * 128},
        {Whh0, Whh0f, 512, 128, 136, 512 * 136},
        {Whh1, Whh1f, 512, 128, 136, 512 * 136},
        {Wp1,  Wp1f,  64, 128, 128, 64 * 128},
        {Wp2,  Wp2f,  22, 64, 64, 32 * 64},
    };
    for (int i = 0; i < 6; i++) {
      int g = (jobs[i].tot + 255) / 256;
      k_prep<<<g, 256, 0, stream>>>(jobs[i].s, jobs[i].d, jobs[i].sr, jobs[i].sc, jobs[i].dc, jobs[i].tot);
    }
  }

  int nch = NT / tc;
  for (int cidx = 0; cidx < nch; cidx++) {
    int t0 = cidx * tc;
    int first = (cidx == 0) ? 1 : 0;
    k_ln<<<dim3(1024 * tc / 32), 256, 0, stream>>>(x, gam, bet, xn, t0, tc);
    k_gates<160><<<dim3(tc, 4, 8), 256, lds1, stream>>>(xn, 160, (long long)tc * 160, Wih0f, b0, xg);
    k_fused<<<dim3(64), 512, ldsF, stream>>>(xg, Whh0f, Wih1f, Whh1f, b1, hsq, ch0, cc0, ch1, cc1, tc, first);
    k_proj<<<dim3(tc, 8), 256, lds5, stream>>>(hsq, Wp1f, Wp2f, bp1, bp2, out, tc, t0);
  }
}